// Round 1
// baseline (192.529 us; speedup 1.0000x reference)
//
#include <hip/hip_runtime.h>

// 5x5 normalized box blur, REFLECT_101 padding, fp32, NCHW 32x3x512x512.
// One block = one 64x64 output tile of one (b,c) plane.
// LDS: stage 68x68 input tile -> horizontal 5-tap -> vertical 5-tap -> store.

#define TILE 64
#define HALO 2
#define TIN  (TILE + 2 * HALO)   // 68
#define PADI (TIN + 1)           // 69, break stride-68 patterns

__global__ __launch_bounds__(256) void smooth_box5_kernel(
    const float* __restrict__ in, float* __restrict__ out, int H, int W)
{
    __shared__ float s_in[TIN][PADI];  // 68 x 69
    __shared__ float s_h [TIN][TILE];  // 68 x 64 (row-blurred)

    const int tid   = threadIdx.x;
    const int tileX = blockIdx.x * TILE;
    const int tileY = blockIdx.y * TILE;
    const long long plane = blockIdx.z;

    const float* __restrict__ ip = in  + plane * (long long)H * W;
    float*       __restrict__ op = out + plane * (long long)H * W;

    // ---- stage 68x68 with REFLECT_101 ----
    #pragma unroll 4
    for (int i = tid; i < TIN * TIN; i += 256) {
        int r = i / TIN;
        int c = i - r * TIN;
        int gy = tileY + r - HALO;
        int gx = tileX + c - HALO;
        gy = (gy < 0) ? -gy : ((gy >= H) ? (2 * H - 2 - gy) : gy);
        gx = (gx < 0) ? -gx : ((gx >= W) ? (2 * W - 2 - gx) : gx);
        s_in[r][c] = ip[(long long)gy * W + gx];
    }
    __syncthreads();

    // ---- horizontal 5-tap: 68 rows x 64 cols ----
    #pragma unroll 4
    for (int i = tid; i < TIN * TILE; i += 256) {
        int r = i >> 6;          // /64
        int c = i & (TILE - 1);  // %64
        float v = s_in[r][c] + s_in[r][c + 1] + s_in[r][c + 2]
                + s_in[r][c + 3] + s_in[r][c + 4];
        s_h[r][c] = v * 0.2f;
    }
    __syncthreads();

    // ---- vertical 5-tap: 64x64, coalesced store ----
    #pragma unroll 4
    for (int i = tid; i < TILE * TILE; i += 256) {
        int r = i >> 6;
        int c = i & (TILE - 1);
        float v = s_h[r][c] + s_h[r + 1][c] + s_h[r + 2][c]
                + s_h[r + 3][c] + s_h[r + 4][c];
        op[(long long)(tileY + r) * W + (tileX + c)] = v * 0.2f;
    }
}

extern "C" void kernel_launch(void* const* d_in, const int* in_sizes, int n_in,
                              void* d_out, int out_size, void* d_ws, size_t ws_size,
                              hipStream_t stream) {
    const float* img = (const float*)d_in[0];
    float* out = (float*)d_out;
    // Shapes fixed by the reference: (32, 3, 512, 512), w = 5 (halo 2).
    const int B = 32, C = 3, H = 512, W = 512;
    dim3 grid(W / TILE, H / TILE, B * C);  // 8 x 8 x 96
    dim3 block(256);
    smooth_box5_kernel<<<grid, block, 0, stream>>>(img, out, H, W);
}